// Round 1
// baseline (486.956 us; speedup 1.0000x reference)
//
#include <hip/hip_runtime.h>

// Problem constants (from reference): B=8, T=4096, D=256, H=8, K=1024, DH=32
#define BB 8
#define TT 4096
#define DD 256
#define HH 8
#define KK 1024
#define DHH 32

#define Q_ELEMS ((size_t)BB * TT * DD)   // 8388608 quantize floats
// out layout: [quantize Q_ELEMS][commit_loss 1][embed_ind B*T*H as float]

// Precompute |e|^2 per (head, code) into workspace: 8*1024 floats = 32 KB.
__global__ void ee_kernel(const float* __restrict__ embeds, float* __restrict__ ee) {
    int i = blockIdx.x * blockDim.x + threadIdx.x;   // 0 .. H*K-1
    if (i < HH * KK) {
        const float* e = embeds + (size_t)i * DHH;
        float s = 0.f;
#pragma unroll
        for (int d = 0; d < DHH; ++d) s = fmaf(e[d], e[d], s);
        ee[i] = s;
    }
}

// One wave (64 lanes) handles 64 consecutive tokens for ONE head.
// Lane-private x chunk in VGPRs; embeds row is wave-uniform -> scalar loads.
__global__ __launch_bounds__(256) void vq_kernel(const float* __restrict__ x,
                                                 const float* __restrict__ embeds,
                                                 const float* __restrict__ ee,
                                                 float* __restrict__ out) {
    int g = blockIdx.x * 256 + threadIdx.x;
    int lane = threadIdx.x & 63;
    int wave = g >> 6;                 // 0 .. B*T*H/64 - 1 = 4095
    int head = wave & (HH - 1);        // wave-uniform
    head = __builtin_amdgcn_readfirstlane(head);   // force SGPR -> s_load for embeds
    int tb = wave >> 3;                // token block 0..511
    int tk = tb * 64 + lane;           // token 0..32767

    // Load this lane's x chunk (32 floats) into registers.
    const float* xr = x + (size_t)tk * DD + head * DHH;
    float xv[DHH];
#pragma unroll
    for (int d = 0; d < DHH; d += 4) {
        float4 v = *reinterpret_cast<const float4*>(xr + d);
        xv[d] = v.x; xv[d + 1] = v.y; xv[d + 2] = v.z; xv[d + 3] = v.w;
    }

    const float* eh  = embeds + (size_t)head * KK * DHH;
    const float* eeh = ee + head * KK;

    float best = -3.4e38f;
    int bestk = 0;
#pragma unroll 2
    for (int k = 0; k < KK; ++k) {
        const float* er = eh + (size_t)k * DHH;    // wave-uniform address
        float dot = 0.f;
#pragma unroll
        for (int d = 0; d < DHH; ++d) dot = fmaf(er[d], xv[d], dot);
        float score = 2.f * dot - eeh[k];
        if (score > best) { best = score; bestk = k; }   // strict > = first-occurrence argmax
    }

    // Gather winning code row -> quantize output.
    float* q = out + (size_t)tk * DD + head * DHH;
    const float* win = eh + (size_t)bestk * DHH;
#pragma unroll
    for (int d = 0; d < DHH; d += 4) {
        *reinterpret_cast<float4*>(q + d) = *reinterpret_cast<const float4*>(win + d);
    }

    // embed_ind as float (d_out is one flat f32 buffer).
    out[Q_ELEMS + 1 + (size_t)tk * HH + head] = (float)bestk;

    // commit_loss scalar = 0.0
    if (g == 0) out[Q_ELEMS] = 0.0f;
}

extern "C" void kernel_launch(void* const* d_in, const int* in_sizes, int n_in,
                              void* d_out, int out_size, void* d_ws, size_t ws_size,
                              hipStream_t stream) {
    const float* x      = (const float*)d_in[0];
    // d_in[1] = x_len (unused by reference forward)
    const float* embeds = (const float*)d_in[2];
    float* out = (float*)d_out;
    float* ee  = (float*)d_ws;   // 32 KB scratch for |e|^2 table

    ee_kernel<<<(HH * KK + 255) / 256, 256, 0, stream>>>(embeds, ee);

    int total_waves = BB * TT * HH / 64;            // 4096 waves
    int blocks = total_waves / 4;                   // 256 threads = 4 waves/block
    vq_kernel<<<blocks, 256, 0, stream>>>(x, embeds, ee, out);
}